// Round 1
// baseline (48.573 us; speedup 1.0000x reference)
//
#include <hip/hip_runtime.h>

// RBF interpolation weights:
//   sparse_coords: [B=4, N=256, 3] f32
//   grid_coords:   [M=65536, 3] f32
//   out:           [B, M, N] f32, softmax-like normalized exp(-d2/(2*sigma^2))
//
// Memory-bound: 256 MiB output write dominates. Each wave handles MPW m-values;
// each lane owns 4 sparse points in registers (n = lane + j*64), so the inner
// loop is pure FMA + v_exp + coalesced stores. No LDS needed.

constexpr int B_ = 4;
constexpr int N_ = 256;
constexpr int M_ = 65536;
constexpr float INV_2SIG2 = 50.0f;  // 1 / (2 * 0.1^2)
constexpr int MPW = 8;              // m-values per wave

__global__ __launch_bounds__(256) void rbf_weights_kernel(
    const float* __restrict__ sparse,  // [B, N, 3]
    const float* __restrict__ grid,    // [M, 3]
    float* __restrict__ out)           // [B, M, N]
{
    const int tid  = threadIdx.x;
    const int lane = tid & 63;
    const int wave = tid >> 6;
    const int b    = blockIdx.y;
    const int m0   = (blockIdx.x * 4 + wave) * MPW;

    // Per-lane sparse points: n = j*64 + lane, kept in registers for all m.
    float sx[4], sy[4], sz[4], s2[4];
    const float* sp = sparse + (size_t)b * N_ * 3;
#pragma unroll
    for (int j = 0; j < 4; ++j) {
        const int n = j * 64 + lane;
        const float x = sp[n * 3 + 0];
        const float y = sp[n * 3 + 1];
        const float z = sp[n * 3 + 2];
        sx[j] = x; sy[j] = y; sz[j] = z;
        s2[j] = x * x + y * y + z * z;
    }

    float* outb = out + ((size_t)b * M_ + m0) * N_;

    for (int mi = 0; mi < MPW; ++mi) {
        const float* g = grid + (size_t)(m0 + mi) * 3;
        const float gx = g[0], gy = g[1], gz = g[2];
        const float g2 = gx * gx + gy * gy + gz * gz;

        float w[4];
        float lsum = 0.0f;
#pragma unroll
        for (int j = 0; j < 4; ++j) {
            float d2 = g2 + s2[j] - 2.0f * (gx * sx[j] + gy * sy[j] + gz * sz[j]);
            d2 = fmaxf(d2, 0.0f);
            const float e = __expf(-d2 * INV_2SIG2);
            w[j] = e;
            lsum += e;
        }

        // Wave-wide sum over 64 lanes.
#pragma unroll
        for (int off = 32; off; off >>= 1) lsum += __shfl_xor(lsum, off);

        const float inv = 1.0f / (lsum + 1e-8f);

        float* o = outb + (size_t)mi * N_;
#pragma unroll
        for (int j = 0; j < 4; ++j) {
            o[j * 64 + lane] = w[j] * inv;
        }
    }
}

extern "C" void kernel_launch(void* const* d_in, const int* in_sizes, int n_in,
                              void* d_out, int out_size, void* d_ws, size_t ws_size,
                              hipStream_t stream) {
    const float* sparse = (const float*)d_in[0];  // [4, 256, 3]
    const float* grid   = (const float*)d_in[1];  // [65536, 3]
    float* out = (float*)d_out;                   // [4, 65536, 256]

    // waves per b = M/MPW = 8192 -> blocks per b = 2048 (4 waves/block)
    dim3 grid_dim(M_ / (4 * MPW), B_, 1);
    dim3 block_dim(256, 1, 1);
    rbf_weights_kernel<<<grid_dim, block_dim, 0, stream>>>(sparse, grid, out);
}

// Round 2
// 47.304 us; speedup vs baseline: 1.0268x; 1.0268x over previous
//
#include <hip/hip_runtime.h>

// RBF interpolation weights:
//   sparse_coords: [B=4, N=256, 3] f32
//   grid_coords:   [M=65536, 3] f32
//   out:           [B, M, N] f32, normalized exp(-d2/(2*sigma^2))
//
// Write-bound (268 MB out). Ceiling measured on this device by the harness's
// fill kernel: ~7.0 TB/s. Key changes vs R0: float4 stores (lane owns
// n = 4*lane..4*lane+3), and all grid coords for the wave's MPW m-values
// prefetched into registers before the compute loop.

constexpr int B_ = 4;
constexpr int N_ = 256;
constexpr int M_ = 65536;
constexpr float INV_2SIG2 = 50.0f;  // 1 / (2 * 0.1^2)
constexpr int MPW = 8;              // m-values per wave

__global__ __launch_bounds__(256) void rbf_weights_kernel(
    const float* __restrict__ sparse,  // [B, N, 3]
    const float* __restrict__ grid,    // [M, 3]
    float* __restrict__ out)           // [B, M, N]
{
    const int tid  = threadIdx.x;
    const int lane = tid & 63;
    const int wave = tid >> 6;
    const int b    = blockIdx.y;
    const int m0   = (blockIdx.x * 4 + wave) * MPW;

    // Per-lane sparse points: n = 4*lane + k, contiguous so the output store
    // is one float4 per lane. 12 contiguous floats per lane -> 3 float4 loads.
    const float* sp = sparse + (size_t)b * N_ * 3 + (size_t)lane * 12;
    const float4 p0 = *(const float4*)(sp + 0);   // x0 y0 z0 x1
    const float4 p1 = *(const float4*)(sp + 4);   // y1 z1 x2 y2
    const float4 p2 = *(const float4*)(sp + 8);   // z2 x3 y3 z3

    float sx[4] = {p0.x, p0.w, p1.z, p2.y};
    float sy[4] = {p0.y, p1.x, p1.w, p2.z};
    float sz[4] = {p0.z, p1.y, p2.x, p2.w};
    float s2[4];
#pragma unroll
    for (int j = 0; j < 4; ++j)
        s2[j] = sx[j] * sx[j] + sy[j] * sy[j] + sz[j] * sz[j];

    // Prefetch all MPW grid points into registers (loads pipeline in prologue).
    float gx[MPW], gy[MPW], gz[MPW];
    const float* g = grid + (size_t)m0 * 3;
#pragma unroll
    for (int mi = 0; mi < MPW; ++mi) {
        gx[mi] = g[mi * 3 + 0];
        gy[mi] = g[mi * 3 + 1];
        gz[mi] = g[mi * 3 + 2];
    }

    float* outb = out + ((size_t)b * M_ + m0) * N_ + (size_t)lane * 4;

#pragma unroll
    for (int mi = 0; mi < MPW; ++mi) {
        const float g2 = gx[mi] * gx[mi] + gy[mi] * gy[mi] + gz[mi] * gz[mi];

        float w[4];
        float lsum = 0.0f;
#pragma unroll
        for (int j = 0; j < 4; ++j) {
            float d2 = g2 + s2[j]
                     - 2.0f * (gx[mi] * sx[j] + gy[mi] * sy[j] + gz[mi] * sz[j]);
            d2 = fmaxf(d2, 0.0f);
            const float e = __expf(-d2 * INV_2SIG2);
            w[j] = e;
            lsum += e;
        }

        // Wave-wide sum over 64 lanes (covers all n regardless of ownership order).
#pragma unroll
        for (int off = 32; off; off >>= 1) lsum += __shfl_xor(lsum, off);

        const float inv = 1.0f / (lsum + 1e-8f);

        float4 o4;
        o4.x = w[0] * inv;
        o4.y = w[1] * inv;
        o4.z = w[2] * inv;
        o4.w = w[3] * inv;
        *(float4*)(outb + (size_t)mi * N_) = o4;
    }
}

extern "C" void kernel_launch(void* const* d_in, const int* in_sizes, int n_in,
                              void* d_out, int out_size, void* d_ws, size_t ws_size,
                              hipStream_t stream) {
    const float* sparse = (const float*)d_in[0];  // [4, 256, 3]
    const float* grid   = (const float*)d_in[1];  // [65536, 3]
    float* out = (float*)d_out;                   // [4, 65536, 256]

    dim3 grid_dim(M_ / (4 * MPW), B_, 1);  // 2048 x 4
    dim3 block_dim(256, 1, 1);
    rbf_weights_kernel<<<grid_dim, block_dim, 0, stream>>>(sparse, grid, out);
}